// Round 4
// baseline (302.290 us; speedup 1.0000x reference)
//
#include <hip/hip_runtime.h>
#include <hip/hip_bf16.h>

typedef short short8 __attribute__((ext_vector_type(8)));
typedef float f32x4 __attribute__((ext_vector_type(4)));

// LDS arena 81920 B = exactly 160KiB/2 -> 2 blocks/CU.
// [0,64K)   XN bf16 xn^T [w][c]        (P2->P3)
//           then XS fp8 x [c][v] [0,32K) + AT fp8 A [w][v] [48K,64K)  (post-P3 -> P4)
//           then YTH bf16 Y^T [w][c] [0,32K)   (P5, after post-P4 barrier)
//           then FLD bf16 F packed [0,64K)     (post-P5)
// [64K,72K) GB (P3)  || overlay NW/NB/UU/MUO/RSO/UDO (P0-P2, dead before GB writes)
// [72K,80K) SUMO/SQO (P1-P2) || overlay BV/BT (staged at P3-start, read at epilogue)
#define XN 0
#define XS 0
#define AT 49152
#define YTH 0
#define FLD 0
#define GB 65536
#define NW 65536
#define NB 66560
#define UU 67584
#define MUO 68608
#define RSO 69120
#define UDO 69632
#define SUMO 73728
#define SQO 77824
#define BV 73728
#define BT 74752
#define LDS_BYTES 81920

__device__ inline unsigned short cvtbf(float f){
  unsigned int x = __float_as_uint(f);
  x += 0x7fffu + ((x >> 16) & 1u);           // RNE
  return (unsigned short)(x >> 16);
}
__device__ inline float bf2f(unsigned short u){ return __uint_as_float(((unsigned int)u) << 16); }
__device__ inline unsigned int pk2(float a, float b){ return (unsigned int)cvtbf(a) | ((unsigned int)cvtbf(b) << 16); }
__device__ inline float lo16(unsigned int v){ return bf2f((unsigned short)(v & 0xffffu)); }
__device__ inline float hi16(unsigned int v){ return bf2f((unsigned short)(v >> 16)); }

// setup: M = wq^T wk (bf16), wv -> bf16, u = wk^T bq. 64 blocks x 4 rows each.
__global__ void __launch_bounds__(256) setup_kernel(
    const float* __restrict__ wq, const float* __restrict__ bq,
    const float* __restrict__ wk, const float* __restrict__ wvw,
    unsigned short* __restrict__ Mbf, unsigned short* __restrict__ wvbf, float* __restrict__ u){
  int t = threadIdx.x;
  int c1b = blockIdx.x * 4;
  float acc[4] = {0.f,0.f,0.f,0.f};
  for (int o = 0; o < 256; ++o){
    float wkv = wk[o*256 + t];
    #pragma unroll
    for (int i = 0; i < 4; ++i) acc[i] = fmaf(wq[o*256 + c1b + i], wkv, acc[i]);
  }
  #pragma unroll
  for (int i = 0; i < 4; ++i){
    Mbf[(c1b+i)*256 + t] = cvtbf(acc[i]);
    wvbf[(c1b+i)*256 + t] = cvtbf(wvw[(c1b+i)*256 + t]);
  }
  if (blockIdx.x == 0){
    float a2 = 0.f;
    for (int o = 0; o < 256; ++o) a2 = fmaf(wk[o*256 + t], bq[o], a2);
    u[t] = a2;
  }
}

__global__ void __launch_bounds__(512, 4) fused_kernel(
    const float* __restrict__ x, const float* __restrict__ nw, const float* __restrict__ nbp,
    const float* __restrict__ bvv, const float* __restrict__ beta,
    const unsigned short* __restrict__ Mbf, const unsigned short* __restrict__ wvbf,
    const float* __restrict__ u, float* __restrict__ out){
  extern __shared__ char smem[];
  const int t = threadIdx.x;
  const int lane = t & 63, wv8 = t >> 6;      // 8 waves
  const int g = lane >> 4, li = lane & 15;
  const int b = blockIdx.x >> 7, h = blockIdx.x & 127;
  const size_t base = (size_t)b*4194304 + (size_t)h*128;  // x[b,c,h,w] = base + c*16384 + w

  // ---- P0: stage norm params into LDS (GB-overlay region, dead before P3's GB writes)
  if (t < 256){
    ((float*)(smem + NW))[t] = nw[t];
    ((float*)(smem + NB))[t] = nbp[t];
    ((float*)(smem + UU))[t] = u[t];
  }

  // ---- P1: coalesced float2 x loads (512B/wave), per-w stats; keep x bf16-packed in xp
  const int w2 = t & 63, s = t >> 6;          // s == wv8; thread owns c in [s*32,s*32+32), w in {2w2, 2w2+1}
  unsigned int xp[32];                         // xp[j] = (bf16 x[s*32+j][2w2], bf16 x[..][2w2+1])
  {
    const float* xw = x + base + (size_t)(s*32)*16384 + 2*w2;
    float sm0 = 0.f, sq0 = 0.f, sm1 = 0.f, sq1 = 0.f;
    #pragma unroll
    for (int j = 0; j < 32; ++j){
      float2 v = *(const float2*)(xw + (size_t)j*16384);
      sm0 += v.x; sq0 = fmaf(v.x, v.x, sq0);
      sm1 += v.y; sq1 = fmaf(v.y, v.y, sq1);
      xp[j] = pk2(v.x, v.y);
    }
    ((float*)(smem + SUMO))[s*128 + 2*w2]     = sm0;
    ((float*)(smem + SUMO))[s*128 + 2*w2 + 1] = sm1;
    ((float*)(smem + SQO))[s*128 + 2*w2]      = sq0;
    ((float*)(smem + SQO))[s*128 + 2*w2 + 1]  = sq1;
  }
  __syncthreads();
  if (t < 128){
    float sm = 0.f, sq = 0.f;
    #pragma unroll
    for (int q = 0; q < 8; ++q){ sm += ((float*)(smem+SUMO))[q*128+t]; sq += ((float*)(smem+SQO))[q*128+t]; }
    float mu = sm * (1.f/256.f);
    float var = sq * (1.f/256.f) - mu*mu;
    ((float*)(smem+MUO))[t] = mu;
    ((float*)(smem+RSO))[t] = rsqrtf(var + 1e-6f);
  }
  __syncthreads();

  // ---- P2: xn^T [w][c] from registers (2 w-rows per thread); udot partials
  {
    float ud[2] = {0.f, 0.f};
    #pragma unroll
    for (int r = 0; r < 2; ++r){
      int w = 2*w2 + r;
      float mu = ((float*)(smem+MUO))[w], rs = ((float*)(smem+RSO))[w];
      #pragma unroll
      for (int i = 0; i < 4; ++i){
        int c0 = s*32 + i*8;
        short8 o8;
        #pragma unroll
        for (int j = 0; j < 8; ++j){
          int c = c0 + j;
          unsigned int p = xp[i*8 + j];
          float xv = bf2f((unsigned short)(r ? (p >> 16) : (p & 0xffffu)));
          float nv = (xv - mu)*rs*((float*)(smem+NW))[c] + ((float*)(smem+NB))[c];
          ud[r] = fmaf(((float*)(smem+UU))[c], nv, ud[r]);
          o8[j] = (short)cvtbf(nv);
        }
        *(short8*)(smem + XN + w*512 + ((2*c0) ^ ((w&31)<<4))) = o8;
      }
    }
    __syncthreads();   // stat reads of SUMO done; safe to overwrite with ud partials
    ((float*)(smem+SUMO))[s*128 + 2*w2]     = ud[0];
    ((float*)(smem+SUMO))[s*128 + 2*w2 + 1] = ud[1];
  }
  __syncthreads();
  if (t < 128){
    float ud = 0.f;
    #pragma unroll
    for (int q = 0; q < 8; ++q) ud += ((float*)(smem+SUMO))[q*128+t];
    ((float*)(smem+UDO))[t] = ud;
  }
  __syncthreads();

  // ---- P3-start: stage bv/beta (SUMO dead now); Sacc init from UDO
  if (t < 256){
    ((float*)(smem + BV))[t] = bvv[t];
    ((float*)(smem + BT))[t] = beta[t];
  }
  f32x4 Sacc[8];
  #pragma unroll
  for (int vt = 0; vt < 8; ++vt){
    int vb = vt*16 + g*4;
    #pragma unroll
    for (int r = 0; r < 4; ++r) Sacc[vt][r] = ((float*)(smem+UDO))[vb + r];
  }
  const int ot = wv8 >> 2, vp = wv8 & 3;
  const int wt = wv8;
  #pragma unroll
  for (int k8 = 0; k8 < 8; ++k8){
    // G band: this wave computes 16 o' x 32 v
    f32x4 Ga[2] = {{0.f,0.f,0.f,0.f},{0.f,0.f,0.f,0.f}};
    const int o = k8*32 + ot*16 + li;
    __builtin_amdgcn_s_setprio(1);
    #pragma unroll
    for (int kk = 0; kk < 8; ++kk){
      short8 afr = *(const short8*)(Mbf + o*256 + kk*32 + g*8);
      #pragma unroll
      for (int j = 0; j < 2; ++j){
        int v = (vp*2 + j)*16 + li;
        short8 bfr = *(const short8*)(smem + XN + v*512 + ((2*(kk*32 + g*8)) ^ ((v&31)<<4)));
        Ga[j] = __builtin_amdgcn_mfma_f32_16x16x32_bf16(afr, bfr, Ga[j], 0, 0, 0);
      }
    }
    __builtin_amdgcn_s_setprio(0);
    __syncthreads();  // prev band's S reads of GB complete
    #pragma unroll
    for (int j = 0; j < 2; ++j){
      int v = (vp*2 + j)*16 + li;
      int ob = ot*16 + g*4;
      uint2 p; p.x = pk2(Ga[j][0], Ga[j][1]); p.y = pk2(Ga[j][2], Ga[j][3]);
      *(uint2*)(smem + GB + v*64 + ((2*ob) ^ ((v&3)<<4))) = p;
    }
    __syncthreads();
    {
      int ww = wt*16 + li;
      short8 bfr = *(const short8*)(smem + XN + ww*512 + ((2*(k8*32 + g*8)) ^ ((ww&31)<<4)));
      __builtin_amdgcn_s_setprio(1);
      #pragma unroll
      for (int vt = 0; vt < 8; ++vt){
        int v = vt*16 + li;
        short8 afr = *(const short8*)(smem + GB + v*64 + ((16*g) ^ ((v&3)<<4)));
        Sacc[vt] = __builtin_amdgcn_mfma_f32_16x16x32_bf16(afr, bfr, Sacc[vt], 0, 0, 0);
      }
      __builtin_amdgcn_s_setprio(0);
    }
  }
  __syncthreads();   // XN fully dead

  // ---- XS: x -> fp8 [c][v] from xp registers (32KB)
  #pragma unroll
  for (int j = 0; j < 32; ++j){
    int c = s*32 + j;
    int pr = __builtin_amdgcn_cvt_pk_fp8_f32(lo16(xp[j]), hi16(xp[j]), 0, false);
    *(unsigned short*)(smem + XS + c*128 + ((2*w2) ^ ((c&15)<<3))) = (unsigned short)pr;
  }

  // ---- softmax over v (rows of S^T), write A as fp8 [w][v] (16KB)
  float mx = -3.4e38f;
  #pragma unroll
  for (int vt = 0; vt < 8; ++vt)
    #pragma unroll
    for (int r = 0; r < 4; ++r){ float sv = Sacc[vt][r]*0.0625f; Sacc[vt][r] = sv; mx = fmaxf(mx, sv); }
  mx = fmaxf(mx, __shfl_xor(mx, 16));
  mx = fmaxf(mx, __shfl_xor(mx, 32));
  float sum = 0.f;
  #pragma unroll
  for (int vt = 0; vt < 8; ++vt)
    #pragma unroll
    for (int r = 0; r < 4; ++r){ float p = exp2f((Sacc[vt][r]-mx)*1.44269504f); Sacc[vt][r] = p; sum += p; }
  sum += __shfl_xor(sum, 16);
  sum += __shfl_xor(sum, 32);
  float inv = 1.f / sum;
  {
    int ww = wt*16 + li;
    #pragma unroll
    for (int vt = 0; vt < 8; ++vt){
      int pr = __builtin_amdgcn_cvt_pk_fp8_f32(Sacc[vt][0]*inv, Sacc[vt][1]*inv, 0, false);
      pr = __builtin_amdgcn_cvt_pk_fp8_f32(Sacc[vt][2]*inv, Sacc[vt][3]*inv, pr, true);
      *(unsigned int*)(smem + AT + ww*128 + ((vt*16 + g*4) ^ ((ww&15)<<3))) = (unsigned int)pr;
    }
  }
  __syncthreads();

  // ---- P4: Y[c][w] = sum_v x[c][v] A[w][v], all-fp8 MFMA from LDS
  f32x4 Yacc[2][8];
  #pragma unroll
  for (int ci = 0; ci < 2; ++ci)
    #pragma unroll
    for (int w2i = 0; w2i < 8; ++w2i) Yacc[ci][w2i] = (f32x4){0.f,0.f,0.f,0.f};
  #pragma unroll
  for (int kk = 0; kk < 4; ++kk){
    long af[2];
    #pragma unroll
    for (int ci = 0; ci < 2; ++ci){
      int c = (wv8*2 + ci)*16 + li;
      af[ci] = *(const long*)(smem + XS + c*128 + ((kk*32 + g*8) ^ ((c&15)<<3)));
    }
    __builtin_amdgcn_s_setprio(1);
    #pragma unroll
    for (int w2i = 0; w2i < 8; ++w2i){
      int ww = w2i*16 + li;
      long bf = *(const long*)(smem + AT + ww*128 + ((kk*32 + g*8) ^ ((ww&15)<<3)));
      #pragma unroll
      for (int ci = 0; ci < 2; ++ci)
        Yacc[ci][w2i] = __builtin_amdgcn_mfma_f32_16x16x32_fp8_fp8(af[ci], bf, Yacc[ci][w2i], 0, 0, 0);
    }
    __builtin_amdgcn_s_setprio(0);
  }
  __syncthreads();   // XS/AT dead; YTH region ([0,32K)) safe to write

  // ---- P5: F[o][w] = sum_c wv[o][c] Y[c][w], two 128-c halves through 32KB YTH
  f32x4 Facc[2][8];
  #pragma unroll
  for (int oi = 0; oi < 2; ++oi)
    #pragma unroll
    for (int w2i = 0; w2i < 8; ++w2i) Facc[oi][w2i] = (f32x4){0.f,0.f,0.f,0.f};
  #pragma unroll
  for (int half = 0; half < 2; ++half){
    if ((wv8 >> 2) == half){
      #pragma unroll
      for (int ci = 0; ci < 2; ++ci){
        int cb = ((wv8 & 3)*2 + ci)*16 + g*4;   // c' within half
        #pragma unroll
        for (int w2i = 0; w2i < 8; ++w2i){
          int ww = w2i*16 + li;
          uint2 p; p.x = pk2(Yacc[ci][w2i][0], Yacc[ci][w2i][1]); p.y = pk2(Yacc[ci][w2i][2], Yacc[ci][w2i][3]);
          *(uint2*)(smem + YTH + ww*256 + ((2*cb) ^ ((ww&15)<<4))) = p;
        }
      }
    }
    __syncthreads();
    #pragma unroll
    for (int kk = 0; kk < 4; ++kk){
      short8 afr[2];
      #pragma unroll
      for (int oi = 0; oi < 2; ++oi){
        int o = (wv8*2 + oi)*16 + li;
        afr[oi] = *(const short8*)(wvbf + o*256 + half*128 + kk*32 + g*8);
      }
      __builtin_amdgcn_s_setprio(1);
      #pragma unroll
      for (int w2i = 0; w2i < 8; ++w2i){
        int ww = w2i*16 + li;
        short8 bfr = *(const short8*)(smem + YTH + ww*256 + ((2*(kk*32 + g*8)) ^ ((ww&15)<<4)));
        #pragma unroll
        for (int oi = 0; oi < 2; ++oi)
          Facc[oi][w2i] = __builtin_amdgcn_mfma_f32_16x16x32_bf16(afr[oi], bfr, Facc[oi][w2i], 0, 0, 0);
      }
      __builtin_amdgcn_s_setprio(0);
    }
    __syncthreads();
  }

  // ---- F redistribution: Ffin = (F+bv)*beta as bf16, packed (o-pair, w) -> [0,64K)
  #pragma unroll
  for (int oi = 0; oi < 2; ++oi){
    #pragma unroll
    for (int rp = 0; rp < 2; ++rp){
      int o0 = (wv8*2 + oi)*16 + g*4 + 2*rp;   // even o
      int orow = o0 >> 1;
      float bv0 = ((float*)(smem+BV))[o0],   bt0 = ((float*)(smem+BT))[o0];
      float bv1 = ((float*)(smem+BV))[o0+1], bt1 = ((float*)(smem+BT))[o0+1];
      #pragma unroll
      for (int w2i = 0; w2i < 8; ++w2i){
        int w = w2i*16 + li;
        float f0 = (Facc[oi][w2i][2*rp]   + bv0)*bt0;
        float f1 = (Facc[oi][w2i][2*rp+1] + bv1)*bt1;
        *(unsigned int*)(smem + FLD + orow*512 + ((4*w) ^ ((orow&7)<<4))) = pk2(f0, f1);
      }
    }
  }
  __syncthreads();

  // ---- epilogue: out = x(from xp) + Ffin; fully coalesced float2 stores
  #pragma unroll
  for (int j = 0; j < 16; ++j){
    int crow = s*16 + j;                        // = (s*32+2j)>>1
    uint2 u2 = *(const uint2*)(smem + FLD + crow*512 + ((8*w2) ^ ((crow&7)<<4)));
    float2 o0, o1;
    o0.x = lo16(xp[2*j])   + lo16(u2.x);
    o0.y = hi16(xp[2*j])   + lo16(u2.y);
    o1.x = lo16(xp[2*j+1]) + hi16(u2.x);
    o1.y = hi16(xp[2*j+1]) + hi16(u2.y);
    size_t c0 = (size_t)(s*32 + 2*j);
    *(float2*)(out + base + c0*16384 + 2*w2)       = o0;
    *(float2*)(out + base + (c0+1)*16384 + 2*w2)   = o1;
  }
}

extern "C" void kernel_launch(void* const* d_in, const int* in_sizes, int n_in,
                              void* d_out, int out_size, void* d_ws, size_t ws_size,
                              hipStream_t stream) {
  (void)in_sizes; (void)n_in; (void)out_size; (void)ws_size;
  const float* x      = (const float*)d_in[0];
  const float* norm_w = (const float*)d_in[1];
  const float* norm_b = (const float*)d_in[2];
  const float* wq     = (const float*)d_in[3];
  const float* bq     = (const float*)d_in[4];
  const float* wk     = (const float*)d_in[5];
  // d_in[6] = bk: only enters softmax-invariant terms, mathematically dropped
  const float* wvw    = (const float*)d_in[7];
  const float* bvv    = (const float*)d_in[8];
  const float* beta   = (const float*)d_in[9];
  float* out = (float*)d_out;

  unsigned short* Mbf  = (unsigned short*)d_ws;                    // 128 KB
  unsigned short* wvbf = (unsigned short*)((char*)d_ws + 131072);  // 128 KB
  float* u             = (float*)((char*)d_ws + 262144);           // 1 KB

  static bool attr_set = false;
  if (!attr_set) {
    (void)hipFuncSetAttribute((const void*)fused_kernel,
                              hipFuncAttributeMaxDynamicSharedMemorySize, LDS_BYTES);
    attr_set = true;
  }

  setup_kernel<<<64, 256, 0, stream>>>(wq, bq, wk, wvw, Mbf, wvbf, u);
  fused_kernel<<<1024, 512, LDS_BYTES, stream>>>(x, norm_w, norm_b, bvv, beta, Mbf, wvbf, u, out);
}